// Round 14
// baseline (109.849 us; speedup 1.0000x reference)
//
#include <hip/hip_runtime.h>
#include <math.h>

#define KPG    1024
#define KRN    4096
#define NN     5121      // KPG + KRN + 1
#define MPAD   5184      // 81 * 64, padded row count for MFMA GEMMs
#define DIN    128
#define DHID   256
#define DOUT   64
#define NHEAD  4
#define LALPHA 0.2f
#define SEMTH  0.7f
#define QNB0   128
#define QCH0   ((NN + QNB0 - 1) / QNB0)  // 41
#define QNB1   128
#define QCH1   ((NN + QNB1 - 1) / QNB1)  // 41
#define MAXD   32
#define NBLK_NORM ((NN + 1) / 2)         // 2561 two-row normalize blocks

typedef __bf16 bf16x8 __attribute__((ext_vector_type(8)));
typedef float  f32x4  __attribute__((ext_vector_type(4)));

__device__ __forceinline__ float wave_sum(float v){
  #pragma unroll
  for (int o = 32; o > 0; o >>= 1) v += __shfl_down(v, o, 64);
  return v;
}

__device__ __forceinline__ float lrelu(float x){ return x >= 0.f ? x : LALPHA * x; }

// bijective XCD swizzle over a linear grid of nwg blocks (m204)
__device__ __forceinline__ int swz_lin(int orig, int nwg){
  int q = nwg >> 3, r = nwg & 7, xcd = orig & 7, idx = orig >> 3;
  return (xcd < r ? xcd * (q + 1) : r * (q + 1) + (xcd - r) * q) + idx;
}

// ---- K1: merged prep: normalize rows -> nfH; weight transpose -> W*H bf16;
//          one extra block computes s0 min/max.
__global__ __launch_bounds__(256) void k_prep(const float* __restrict__ pv,
                                              const float* __restrict__ rv,
                                              const float* __restrict__ qv,
                                              const float* __restrict__ Win,
                                              const float* __restrict__ Wg0,
                                              const float* __restrict__ Wg1,
                                              const float* __restrict__ s0,
                                              __bf16* __restrict__ nfH,
                                              __bf16* __restrict__ WinH,
                                              __bf16* __restrict__ Wg0H,
                                              __bf16* __restrict__ Wg1H,
                                              float* __restrict__ mm){
  __shared__ float tile[64][65];
  __shared__ float w4[4];
  int b = blockIdx.x, t = threadIdx.x;
  if (b < NBLK_NORM){
    int i = b * 2 + (t >> 7);
    int tt = t & 127;
    float x = 0.f;
    if (i < NN){
      const float* src = (i < KPG) ? pv + (size_t)i * DIN
                       : (i < KPG + KRN) ? rv + (size_t)(i - KPG) * DIN : qv;
      x = src[tt];
    }
    float ss = wave_sum(x * x);
    if ((t & 63) == 0) w4[t >> 6] = ss;
    __syncthreads();
    if (i < NN){
      int rh = t >> 7;
      float norm = sqrtf(w4[2 * rh] + w4[2 * rh + 1]);
      nfH[(size_t)i * DIN + tt] = (__bf16)(x / fmaxf(norm, 1e-12f));
    }
  } else if (b < NBLK_NORM + 136){
    int bb = b - NBLK_NORM;
    const float* W; __bf16 *TH; int K, N, tb;
    if (bb < 8){ W = Win; TH = WinH; K = DIN;  N = DHID; tb = bb; }
    else if (bb < 72){ W = Wg0; TH = Wg0H; K = DHID; N = 1024; tb = bb - 8; }
    else { W = Wg1; TH = Wg1H; K = 1024; N = DHID; tb = bb - 72; }
    int ntx = N >> 6;
    int kb = (tb / ntx) * 64, nb = (tb % ntx) * 64;
    int rr = t >> 6, cc = t & 63;
    #pragma unroll
    for (int i = 0; i < 16; ++i){
      int k = i * 4 + rr;
      tile[k][cc] = W[(size_t)(kb + k) * N + nb + cc];
    }
    __syncthreads();
    #pragma unroll
    for (int i = 0; i < 16; ++i){
      int n = i * 4 + rr;
      TH[(size_t)(nb + n) * K + kb + cc] = (__bf16)tile[cc][n];
    }
  } else {
    float mn = 1e30f, mx = -1e30f;
    for (int j = t; j < KPG; j += 256){
      float v = s0[j];
      mn = fminf(mn, v); mx = fmaxf(mx, v);
    }
    __shared__ float smn[256], smx[256];
    smn[t] = mn; smx[t] = mx;
    __syncthreads();
    for (int s = 128; s > 0; s >>= 1){
      if (t < s){ smn[t] = fminf(smn[t], smn[t + s]); smx[t] = fmaxf(smx[t], smx[t + s]); }
      __syncthreads();
    }
    if (t == 0){ mm[0] = smn[0]; mm[1] = smx[0]; }
  }
}

#define MFMA(a,b,c) __builtin_amdgcn_mfma_f32_16x16x32_bf16(a, b, c, 0, 0, 0)

struct Acc { f32x4 a00, a01, a10, a11; };

// ---- LDS-staged MFMA core, BK=128 (4 waves, 64x64 tile), plain bf16.
// LDS: A 64x128 + B 64x128 bf16 = 32 KB. K=128 -> single step, one barrier pair.
template<int K>
__device__ __forceinline__ Acc gemm_core2(const __bf16* __restrict__ AH,
                                          const __bf16* __restrict__ BH,
                                          int rblk, int cblk,
                                          __bf16* sm){
  int t = threadIdx.x, w = t >> 6, l = t & 63;
  int lr = l & 15, lk = l >> 4;
  __bf16* sA = sm;
  __bf16* sB = sm + 8192;

  int srow = t >> 4, scol = t & 15;          // 16 threads/row, 16B each
  int sw = ((scol ^ (srow & 7)) * 8);        // (row+16k)&7 == row&7
  size_t gA = (size_t)(rblk + srow) * K + scol * 8;
  size_t gB = (size_t)(cblk + srow) * K + scol * 8;

  int ar0 = (w >> 1) * 32 + lr, ar1 = ar0 + 16;
  int bc0 = (w & 1) * 32 + lr,  bc1 = bc0 + 16;

  Acc acc;
  #pragma unroll
  for (int r = 0; r < 4; ++r){ acc.a00[r]=0.f; acc.a01[r]=0.f; acc.a10[r]=0.f; acc.a11[r]=0.f; }

  int4 a0, a1, a2, a3, b0, b1, b2, b3;
  a0 = *(const int4*)(AH + gA);
  a1 = *(const int4*)(AH + gA + (size_t)16 * K);
  a2 = *(const int4*)(AH + gA + (size_t)32 * K);
  a3 = *(const int4*)(AH + gA + (size_t)48 * K);
  b0 = *(const int4*)(BH + gB);
  b1 = *(const int4*)(BH + gB + (size_t)16 * K);
  b2 = *(const int4*)(BH + gB + (size_t)32 * K);
  b3 = *(const int4*)(BH + gB + (size_t)48 * K);

  const int NSTEP = K / 128;
  #pragma unroll 1
  for (int s = 0; s < NSTEP; ++s){
    __syncthreads();
    *(int4*)(sA + (srow     ) * 128 + sw) = a0;
    *(int4*)(sA + (srow + 16) * 128 + sw) = a1;
    *(int4*)(sA + (srow + 32) * 128 + sw) = a2;
    *(int4*)(sA + (srow + 48) * 128 + sw) = a3;
    *(int4*)(sB + (srow     ) * 128 + sw) = b0;
    *(int4*)(sB + (srow + 16) * 128 + sw) = b1;
    *(int4*)(sB + (srow + 32) * 128 + sw) = b2;
    *(int4*)(sB + (srow + 48) * 128 + sw) = b3;
    if (s + 1 < NSTEP){
      size_t ka = (size_t)(s + 1) * 128;
      a0 = *(const int4*)(AH + gA + ka);
      a1 = *(const int4*)(AH + gA + (size_t)16 * K + ka);
      a2 = *(const int4*)(AH + gA + (size_t)32 * K + ka);
      a3 = *(const int4*)(AH + gA + (size_t)48 * K + ka);
      b0 = *(const int4*)(BH + gB + ka);
      b1 = *(const int4*)(BH + gB + (size_t)16 * K + ka);
      b2 = *(const int4*)(BH + gB + (size_t)32 * K + ka);
      b3 = *(const int4*)(BH + gB + (size_t)48 * K + ka);
    }
    __syncthreads();
    #pragma unroll
    for (int kk = 0; kk < 4; ++kk){
      int pc = ((lk + kk * 4) ^ (lr & 7)) * 8;
      bf16x8 A0 = *(const bf16x8*)(sA + ar0 * 128 + pc);
      bf16x8 A1 = *(const bf16x8*)(sA + ar1 * 128 + pc);
      bf16x8 B0 = *(const bf16x8*)(sB + bc0 * 128 + pc);
      bf16x8 B1 = *(const bf16x8*)(sB + bc1 * 128 + pc);
      acc.a00 = MFMA(A0, B0, acc.a00);
      acc.a01 = MFMA(A0, B1, acc.a01);
      acc.a10 = MFMA(A1, B0, acc.a10);
      acc.a11 = MFMA(A1, B1, acc.a11);
    }
  }
  return acc;
}

// ---- K2: merged sim (256 blocks) + hres GEMM (324 blocks), K=128 single-step
__global__ __launch_bounds__(256) void k_simhres(const __bf16* __restrict__ nfH,
                                                 const int* __restrict__ pn,
                                                 const __bf16* __restrict__ WinH,
                                                 const float* __restrict__ bin,
                                                 unsigned char* __restrict__ mask,
                                                 float* __restrict__ hres,
                                                 __bf16* __restrict__ hresH){
  __shared__ __bf16 smem[16384];
  int b = blockIdx.x, t = threadIdx.x;
  int w = t >> 6, l = t & 63, lr = l & 15, lk = l >> 4;
  if (b < 256){
    int wg = swz_lin(b, 256);
    int rblk = (wg >> 4) * 64, cblk = (wg & 15) * 64;
    Acc acc = gemm_core2<DIN>(nfH, nfH, rblk, cblk, smem);
    int rb = rblk + (w >> 1) * 32 + lk * 4;
    int cb = cblk + (w & 1) * 32 + lr;
    #pragma unroll
    for (int m = 0; m < 2; ++m){
      #pragma unroll
      for (int n = 0; n < 2; ++n){
        const f32x4& a = (m == 0) ? (n == 0 ? acc.a00 : acc.a01) : (n == 0 ? acc.a10 : acc.a11);
        int j = cb + n * 16;
        int pnj = pn[j];
        #pragma unroll
        for (int r = 0; r < 4; ++r){
          int i = rb + m * 16 + r;
          float s = a[r];
          int d = pn[i] - pnj;
          bool mb = ((s >= SEMTH) && (j != i)) || (d == 1) || (d == -1) || (j == i);
          mask[(size_t)i * KPG + j] = mb ? 1 : 0;
        }
      }
    }
  } else {
    int bb = swz_lin(b - 256, 324);
    int rblk = (bb >> 2) * 64, cblk = (bb & 3) * 64;
    Acc acc = gemm_core2<DIN>(nfH, WinH, rblk, cblk, smem);
    int rb = rblk + (w >> 1) * 32 + lk * 4;
    int cb = cblk + (w & 1) * 32 + lr;
    #pragma unroll
    for (int m = 0; m < 2; ++m){
      #pragma unroll
      for (int n = 0; n < 2; ++n){
        const f32x4& a = (m == 0) ? (n == 0 ? acc.a00 : acc.a01) : (n == 0 ? acc.a10 : acc.a11);
        int col = cb + n * 16;
        float bv = bin[col];
        #pragma unroll
        for (int r = 0; r < 4; ++r){
          int row = rb + m * 16 + r;
          float v = a[r] + bv;
          size_t o = (size_t)row * DHID + col;
          hres[o] = v;
          hresH[o] = (__bf16)v;
        }
      }
    }
  }
}

// ---- K3: merged wh0 GEMM (1296 blocks, K=256 two-step) + neighbor compaction
__global__ __launch_bounds__(256) void k_nbrwh0(const __bf16* __restrict__ hresH,
                                                const __bf16* __restrict__ Wg0H,
                                                const unsigned char* __restrict__ mask,
                                                __bf16* __restrict__ wh0H,
                                                int* __restrict__ nbr,
                                                int* __restrict__ deg){
  __shared__ __bf16 smem[16384];
  int b = blockIdx.x, t = threadIdx.x;
  if (b < 1296){
    int wg = swz_lin(b, 1296);
    int rblk = (wg >> 4) * 64, cblk = (wg & 15) * 64;
    Acc acc = gemm_core2<DHID>(hresH, Wg0H, rblk, cblk, smem);
    int w = t >> 6, l = t & 63, lr = l & 15, lk = l >> 4;
    int rb = rblk + (w >> 1) * 32 + lk * 4;
    int cb = cblk + (w & 1) * 32 + lr;
    #pragma unroll
    for (int m = 0; m < 2; ++m){
      #pragma unroll
      for (int n = 0; n < 2; ++n){
        const f32x4& a = (m == 0) ? (n == 0 ? acc.a00 : acc.a01) : (n == 0 ? acc.a10 : acc.a11);
        int col = cb + n * 16;
        #pragma unroll
        for (int r = 0; r < 4; ++r)
          wh0H[(size_t)(rb + m * 16 + r) * 1024 + col] = (__bf16)a[r];
      }
    }
  } else {
    int i = (b - 1296) * 4 + (t >> 6);
    int l = t & 63;
    const unsigned char* mrow = mask + (size_t)i * KPG;
    int off = 0;
    #pragma unroll
    for (int c = 0; c < 16; ++c){
      int j = c * 64 + l;
      bool bb = mrow[j] != 0;
      unsigned long long bal = __ballot(bb);
      int pos = off + __popcll(bal & ((1ull << l) - 1ull));
      if (bb && pos < MAXD) nbr[i * MAXD + pos] = j;
      off += __popcll(bal);
    }
    if (l == 0) deg[i] = (off > MAXD) ? MAXD : off;
  }
}

// ---- 8-wave in-block split-K(2) GEMM (wh1, K=1024), BK=128
template<int K>
__global__ __launch_bounds__(512) void k_gemm3s(const __bf16* __restrict__ AH,
                                                const __bf16* __restrict__ BH,
                                                __bf16* __restrict__ Cb,
                                                int N){
  __shared__ __bf16 smem[32768];             // 64 KB: 2 halves x (A+B 64x128)
  int nwg = gridDim.x * gridDim.y;
  int orig = blockIdx.y * gridDim.x + blockIdx.x;
  int wg = swz_lin(orig, nwg);
  int bx = wg % gridDim.x, by = wg / gridDim.x;
  int rblk = by * 64, cblk = bx * 64;
  int t = threadIdx.x, kq = t >> 8, tl = t & 255;
  int w = t >> 6, quad = w & 3, l = t & 63;
  int lr = l & 15, lk = l >> 4;
  const int KH = K / 2;
  int kbase = kq * KH;

  __bf16* sA = smem + kq * 16384;
  __bf16* sB = sA + 8192;

  int srow = tl >> 4, scol = tl & 15;
  int sw = ((scol ^ (srow & 7)) * 8);
  size_t gA = (size_t)(rblk + srow) * K + kbase + scol * 8;
  size_t gB = (size_t)(cblk + srow) * K + kbase + scol * 8;

  int ar0 = (quad >> 1) * 32 + lr, ar1 = ar0 + 16;
  int bc0 = (quad & 1) * 32 + lr,  bc1 = bc0 + 16;

  Acc acc;
  #pragma unroll
  for (int r = 0; r < 4; ++r){ acc.a00[r]=0.f; acc.a01[r]=0.f; acc.a10[r]=0.f; acc.a11[r]=0.f; }

  int4 a0 = *(const int4*)(AH + gA);
  int4 a1 = *(const int4*)(AH + gA + (size_t)16 * K);
  int4 a2 = *(const int4*)(AH + gA + (size_t)32 * K);
  int4 a3 = *(const int4*)(AH + gA + (size_t)48 * K);
  int4 b0 = *(const int4*)(BH + gB);
  int4 b1 = *(const int4*)(BH + gB + (size_t)16 * K);
  int4 b2 = *(const int4*)(BH + gB + (size_t)32 * K);
  int4 b3 = *(const int4*)(BH + gB + (size_t)48 * K);

  const int NSTEP = KH / 128;
  #pragma unroll 1
  for (int s = 0; s < NSTEP; ++s){
    __syncthreads();
    *(int4*)(sA + (srow     ) * 128 + sw) = a0;
    *(int4*)(sA + (srow + 16) * 128 + sw) = a1;
    *(int4*)(sA + (srow + 32) * 128 + sw) = a2;
    *(int4*)(sA + (srow + 48) * 128 + sw) = a3;
    *(int4*)(sB + (srow     ) * 128 + sw) = b0;
    *(int4*)(sB + (srow + 16) * 128 + sw) = b1;
    *(int4*)(sB + (srow + 32) * 128 + sw) = b2;
    *(int4*)(sB + (srow + 48) * 128 + sw) = b3;
    if (s + 1 < NSTEP){
      size_t ka = (size_t)(s + 1) * 128;
      a0 = *(const int4*)(AH + gA + ka);
      a1 = *(const int4*)(AH + gA + (size_t)16 * K + ka);
      a2 = *(const int4*)(AH + gA + (size_t)32 * K + ka);
      a3 = *(const int4*)(AH + gA + (size_t)48 * K + ka);
      b0 = *(const int4*)(BH + gB + ka);
      b1 = *(const int4*)(BH + gB + (size_t)16 * K + ka);
      b2 = *(const int4*)(BH + gB + (size_t)32 * K + ka);
      b3 = *(const int4*)(BH + gB + (size_t)48 * K + ka);
    }
    __syncthreads();
    #pragma unroll
    for (int kk = 0; kk < 4; ++kk){
      int pc = ((lk + kk * 4) ^ (lr & 7)) * 8;
      bf16x8 A0 = *(const bf16x8*)(sA + ar0 * 128 + pc);
      bf16x8 A1 = *(const bf16x8*)(sA + ar1 * 128 + pc);
      bf16x8 B0 = *(const bf16x8*)(sB + bc0 * 128 + pc);
      bf16x8 B1 = *(const bf16x8*)(sB + bc1 * 128 + pc);
      acc.a00 = MFMA(A0, B0, acc.a00);
      acc.a01 = MFMA(A0, B1, acc.a01);
      acc.a10 = MFMA(A1, B0, acc.a10);
      acc.a11 = MFMA(A1, B1, acc.a11);
    }
  }

  __syncthreads();
  float* part = (float*)smem;                // part[2][64][64] f32 = 32 KB
  int rbase = (quad >> 1) * 32, cbase = (quad & 1) * 32;
  #pragma unroll
  for (int m = 0; m < 2; ++m){
    #pragma unroll
    for (int n = 0; n < 2; ++n){
      const f32x4& a = (m == 0) ? (n == 0 ? acc.a00 : acc.a01) : (n == 0 ? acc.a10 : acc.a11);
      #pragma unroll
      for (int r = 0; r < 4; ++r)
        part[kq * 4096 + (rbase + m * 16 + lk * 4 + r) * 64 + cbase + n * 16 + lr] = a[r];
    }
  }
  __syncthreads();
  #pragma unroll
  for (int e = 0; e < 8; ++e){
    int idx = e * 512 + t;
    int row = idx >> 6, col = idx & 63;
    float v = part[idx] + part[4096 + idx];
    Cb[(size_t)(rblk + row) * N + cblk + col] = (__bf16)v;
  }
}

// ---- K5: s/d projections for layer 0
__global__ __launch_bounds__(256) void k_sd0(const __bf16* __restrict__ wh,
                                             const float* __restrict__ asrc,
                                             const float* __restrict__ adst,
                                             float* __restrict__ sd){
  int n = blockIdx.x, t = threadIdx.x, hh = t >> 6, l = t & 63;
  float s = 0.f, d = 0.f;
  #pragma unroll
  for (int k = 0; k < 4; ++k){
    int idx = hh * 256 + k * 64 + l;
    float v = (float)wh[(size_t)n * 1024 + idx];
    s += v * asrc[idx];
    d += v * adst[idx];
  }
  s = wave_sum(s); d = wave_sum(d);
  if (l == 0){ sd[n * 8 + hh] = s; sd[n * 8 + 4 + hh] = d; }
}

// ---- K6: merged GAT layer-0: query partials | pages | region-groups
__global__ __launch_bounds__(256) void k_gat0all(const __bf16* __restrict__ wh,
                                                 const float* __restrict__ sd,
                                                 const int* __restrict__ nbr,
                                                 const int* __restrict__ deg,
                                                 __bf16* __restrict__ h1H,
                                                 float* __restrict__ qpart,
                                                 float* __restrict__ qz){
  int b = blockIdx.x, t = threadIdx.x;
  if (b < QNB0){
    int bq = b;
    float sq[NHEAD];
    #pragma unroll
    for (int h = 0; h < NHEAD; ++h) sq[h] = sd[(size_t)(NN - 1) * 8 + h];
    int j0 = bq * QCH0, j1 = (j0 + QCH0 < NN) ? j0 + QCH0 : NN;
    float acc[NHEAD] = {0.f, 0.f, 0.f, 0.f};
    float z[NHEAD] = {0.f, 0.f, 0.f, 0.f};
    #pragma unroll 4
    for (int j = j0; j < j1; ++j){
      float4 d4 = *(const float4*)&sd[j * 8 + 4];
      float e0 = __expf(lrelu(sq[0] + d4.x));
      float e1 = __expf(lrelu(sq[1] + d4.y));
      float e2 = __expf(lrelu(sq[2] + d4.z));
      float e3 = __expf(lrelu(sq[3] + d4.w));
      z[0] += e0; z[1] += e1; z[2] += e2; z[3] += e3;
      size_t base = (size_t)j * 1024 + t;
      acc[0] += e0 * (float)wh[base];
      acc[1] += e1 * (float)wh[base + 256];
      acc[2] += e2 * (float)wh[base + 512];
      acc[3] += e3 * (float)wh[base + 768];
    }
    #pragma unroll
    for (int h = 0; h < NHEAD; ++h) qpart[(size_t)bq * 1024 + h * 256 + t] = acc[h];
    if (t == 0){
      #pragma unroll
      for (int h = 0; h < NHEAD; ++h) qz[bq * 4 + h] = z[h];
    }
  } else if (b < QNB0 + KPG){
    int i = b - QNB0;
    __shared__ int jl[MAXD + 5];
    __shared__ float wgt[NHEAD][MAXD + 5];
    __shared__ float izs[NHEAD];
    int nd = deg[i], cnt = nd + 5;
    if (t < cnt)
      jl[t] = (t < nd) ? nbr[i * MAXD + t]
                       : ((t < nd + 4) ? (KPG + 4 * i + (t - nd)) : (NN - 1));
    __syncthreads();
    if (t < 4 * cnt){
      int x = t >> 2, h = t & 3;
      wgt[h][x] = __expf(lrelu(sd[i * 8 + h] + sd[jl[x] * 8 + 4 + h]));
    }
    __syncthreads();
    if (t < NHEAD){
      float Z = 0.f;
      for (int x = 0; x < cnt; ++x) Z += wgt[t][x];
      izs[t] = 1.f / Z;
    }
    __syncthreads();
    float acc[NHEAD] = {0.f, 0.f, 0.f, 0.f};
    #pragma unroll 4
    for (int x = 0; x < cnt; ++x){
      size_t base = (size_t)jl[x] * 1024 + t;
      #pragma unroll
      for (int h = 0; h < NHEAD; ++h) acc[h] += wgt[h][x] * (float)wh[base + h * 256];
    }
    size_t ob = (size_t)i * 1024;
    #pragma unroll
    for (int h = 0; h < NHEAD; ++h){
      float v = acc[h] * izs[h];
      v = (v > 0.f) ? v : expm1f(v);
      h1H[ob + h * 256 + t] = (__bf16)v;
    }
  } else {
    int g = b - QNB0 - KPG;
    __shared__ float wgt2[4][NHEAD][6];
    int rb = KPG + 4 * g;
    if (t < 16){
      int r = t >> 2, h = t & 3;
      int i = rb + r;
      float si = sd[i * 8 + h];
      int jx[6] = {g, rb, rb + 1, rb + 2, rb + 3, NN - 1};
      float Z = 0.f, e[6];
      #pragma unroll
      for (int x = 0; x < 6; ++x){
        e[x] = __expf(lrelu(si + sd[jx[x] * 8 + 4 + h]));
        Z += e[x];
      }
      float iz = 1.f / Z;
      #pragma unroll
      for (int x = 0; x < 6; ++x) wgt2[r][h][x] = e[x] * iz;
    }
    __syncthreads();
    float acc[4][NHEAD] = {};
    int jx[6] = {g, rb, rb + 1, rb + 2, rb + 3, NN - 1};
    #pragma unroll
    for (int x = 0; x < 6; ++x){
      size_t base = (size_t)jx[x] * 1024 + t;
      #pragma unroll
      for (int h = 0; h < NHEAD; ++h){
        float v = (float)wh[base + h * 256];
        #pragma unroll
        for (int r = 0; r < 4; ++r) acc[r][h] += wgt2[r][h][x] * v;
      }
    }
    #pragma unroll
    for (int r = 0; r < 4; ++r){
      size_t ob = (size_t)(rb + r) * 1024;
      #pragma unroll
      for (int h = 0; h < NHEAD; ++h){
        float v = acc[r][h];
        v = (v > 0.f) ? v : expm1f(v);
        h1H[ob + h * 256 + t] = (__bf16)v;
      }
    }
  }
}

// ---- finish query row of h1 (one block per head)
__global__ __launch_bounds__(256) void k_qfin0(const float* __restrict__ qpart,
                                               const float* __restrict__ qz,
                                               __bf16* __restrict__ h1H){
  int h = blockIdx.x, t = threadIdx.x;
  float s = 0.f, Z = 0.f;
  #pragma unroll 4
  for (int b = 0; b < QNB0; ++b){
    s += qpart[(size_t)b * 1024 + h * 256 + t];
    Z += qz[b * 4 + h];
  }
  float v = s / Z;
  v = (v > 0.f) ? v : expm1f(v);
  h1H[(size_t)(NN - 1) * 1024 + h * 256 + t] = (__bf16)v;
}

// ---- K8: s/d projections for layer 1
__global__ __launch_bounds__(256) void k_sd1(const __bf16* __restrict__ wh,
                                             const float* __restrict__ asrc,
                                             const float* __restrict__ adst,
                                             float* __restrict__ sd){
  int n = blockIdx.x, t = threadIdx.x, hh = t >> 6, l = t & 63;
  float v = (float)wh[(size_t)n * 256 + hh * 64 + l];
  float s = wave_sum(v * asrc[hh * 64 + l]);
  float d = wave_sum(v * adst[hh * 64 + l]);
  if (l == 0){ sd[n * 8 + hh] = s; sd[n * 8 + 4 + hh] = d; }
}

// ---- K9: merged GAT layer-1: query partials | pages
__global__ __launch_bounds__(256) void k_gat1all(const __bf16* __restrict__ wh,
                                                 const float* __restrict__ sd,
                                                 const int* __restrict__ nbr,
                                                 const int* __restrict__ deg,
                                                 float* __restrict__ h2,
                                                 float* __restrict__ qpart,
                                                 float* __restrict__ qz){
  int b = blockIdx.x, t = threadIdx.x, hh = t >> 6;
  if (b < QNB1){
    int bq = b;
    float sq = sd[(size_t)(NN - 1) * 8 + hh];
    int j0 = bq * QCH1, j1 = (j0 + QCH1 < NN) ? j0 + QCH1 : NN;
    float acc = 0.f, z = 0.f;
    #pragma unroll 4
    for (int j = j0; j < j1; ++j){
      float e = __expf(lrelu(sq + sd[j * 8 + 4 + hh]));
      z += e;
      acc += e * (float)wh[(size_t)j * 256 + t];
    }
    qpart[(size_t)bq * 256 + t] = acc;
    if ((t & 63) == 0) qz[bq * 4 + hh] = z;
  } else {
    int i = b - QNB1;
    __shared__ int jl[MAXD + 5];
    __shared__ float wgt[NHEAD][MAXD + 5];
    __shared__ float izs[NHEAD];
    int nd = deg[i], cnt = nd + 5;
    if (t < cnt)
      jl[t] = (t < nd) ? nbr[i * MAXD + t]
                       : ((t < nd + 4) ? (KPG + 4 * i + (t - nd)) : (NN - 1));
    __syncthreads();
    if (t < 4 * cnt){
      int x = t >> 2, h = t & 3;
      wgt[h][x] = __expf(lrelu(sd[i * 8 + h] + sd[jl[x] * 8 + 4 + h]));
    }
    __syncthreads();
    if (t < NHEAD){
      float Z = 0.f;
      for (int x = 0; x < cnt; ++x) Z += wgt[t][x];
      izs[t] = 1.f / Z;
    }
    __syncthreads();
    float acc = 0.f;
    #pragma unroll 4
    for (int x = 0; x < cnt; ++x)
      acc += wgt[hh][x] * (float)wh[(size_t)jl[x] * 256 + t];
    acc *= izs[hh];
    __shared__ float col[256];
    col[t] = acc;
    __syncthreads();
    if (t < 64)
      h2[(size_t)i * 64 + t] = 0.25f * (col[t] + col[64 + t] + col[128 + t] + col[192 + t]);
  }
}

// ---- finish query row of h2 + fold in the query residual -> qrep[64]
__global__ __launch_bounds__(256) void k_qfin1(const float* __restrict__ qpart,
                                               const float* __restrict__ qz,
                                               const float* __restrict__ hres,
                                               const float* __restrict__ Wres,
                                               const float* __restrict__ bres,
                                               float* __restrict__ qrep){
  int t = threadIdx.x, hh = t >> 6;
  float s = 0.f, Z = 0.f;
  #pragma unroll 4
  for (int b = 0; b < QNB1; ++b){
    s += qpart[(size_t)b * 256 + t];
    Z += qz[b * 4 + hh];
  }
  __shared__ float col[256];
  __shared__ float hq[256];
  col[t] = s / Z;
  hq[t] = hres[(size_t)(NN - 1) * DHID + t];
  __syncthreads();
  if (t < 64){
    float h2q = 0.25f * (col[t] + col[64 + t] + col[128 + t] + col[192 + t]);
    float rq = bres[t];
    #pragma unroll 8
    for (int d = 0; d < DHID; ++d) rq += hq[d] * Wres[d * 64 + t];
    qrep[t] = h2q + rq;
  }
}

// ---- K12: scoring MLP, 4 pages per block (wave per page)
__global__ __launch_bounds__(256) void k_score4(const float* __restrict__ h2,
                                                const float* __restrict__ hres,
                                                const float* __restrict__ Wres,
                                                const float* __restrict__ bres,
                                                const float* __restrict__ Ws1,
                                                const float* __restrict__ bs1,
                                                const float* __restrict__ Ws2,
                                                const float* __restrict__ bs2,
                                                const float* __restrict__ s0,
                                                const float* __restrict__ lmix,
                                                const float* __restrict__ mm,
                                                const float* __restrict__ qrep,
                                                float* __restrict__ out){
  int t = threadIdx.x, w = t >> 6, l = t & 63;
  int i = blockIdx.x * 4 + w;
  __shared__ float hrow[4][DHID];
  __shared__ float qr[64];
  __shared__ float pgs[4][64];
  #pragma unroll
  for (int k = 0; k < 4; ++k)
    hrow[w][k * 64 + l] = hres[(size_t)i * DHID + k * 64 + l];
  if (t < 64) qr[t] = qrep[t];
  __syncthreads();
  float ri = bres[l];
  #pragma unroll 8
  for (int d = 0; d < DHID; ++d) ri += hrow[w][d] * Wres[d * 64 + l];
  pgs[w][l] = h2[(size_t)i * 64 + l] + ri;
  __syncthreads();
  float z = bs1[l];
  #pragma unroll 8
  for (int d = 0; d < 64; ++d){
    z += pgs[w][d] * Ws1[d * 64 + l];
    z += qr[d] * Ws1[(64 + d) * 64 + l];
  }
  z = fmaxf(z, 0.f);
  float v = wave_sum(z * Ws2[l]);
  if (l == 0){
    float delta = v + bs2[0];
    float mn = mm[0], mx = mm[1];
    float s0n = (s0[i] - mn) / (mx - mn + 1e-8f);
    float lam = 1.f / (1.f + __expf(-lmix[0]));
    out[i] = (1.f - lam) * s0n + lam * delta;
  }
}

extern "C" void kernel_launch(void* const* d_in, const int* in_sizes, int n_in,
                              void* d_out, int out_size, void* d_ws, size_t ws_size,
                              hipStream_t stream){
  const float* pv  = (const float*)d_in[0];
  const float* rv  = (const float*)d_in[1];
  const float* qv  = (const float*)d_in[2];
  const int*   pn  = (const int*)d_in[3];
  const float* s0  = (const float*)d_in[4];
  const float* Win = (const float*)d_in[5];
  const float* bin = (const float*)d_in[6];
  const float* Wg0 = (const float*)d_in[7];
  const float* as0 = (const float*)d_in[8];
  const float* ad0 = (const float*)d_in[9];
  const float* Wg1 = (const float*)d_in[10];
  const float* as1 = (const float*)d_in[11];
  const float* ad1 = (const float*)d_in[12];
  const float* Wrs = (const float*)d_in[13];
  const float* brs = (const float*)d_in[14];
  const float* Ws1 = (const float*)d_in[15];
  const float* bs1 = (const float*)d_in[16];
  const float* Ws2 = (const float*)d_in[17];
  const float* bs2 = (const float*)d_in[18];
  const float* lmx = (const float*)d_in[19];
  float* out = (float*)d_out;

  float* ws = (float*)d_ws;
  size_t off = 0;
  __bf16* nfH = (__bf16*)(ws + off); off += (size_t)MPAD * DIN / 2;
  __bf16* WinH = (__bf16*)(ws + off); off += (size_t)DHID * DIN / 2;
  __bf16* Wg0H = (__bf16*)(ws + off); off += (size_t)1024 * DHID / 2;
  __bf16* Wg1H = (__bf16*)(ws + off); off += (size_t)DHID * 1024 / 2;
  float* hres = ws + off; off += (size_t)MPAD * DHID;
  __bf16* hresH = (__bf16*)(ws + off); off += (size_t)MPAD * DHID / 2;
  __bf16* wh0H = (__bf16*)(ws + off); off += (size_t)MPAD * 1024 / 2;
  __bf16* h1H  = (__bf16*)(ws + off); off += (size_t)MPAD * 1024 / 2;
  __bf16* wh1H = (__bf16*)(ws + off); off += (size_t)MPAD * 256 / 2;
  float* sd0  = ws + off; off += (size_t)NN * 8;
  float* sd1  = ws + off; off += (size_t)NN * 8;
  float* h2   = ws + off; off += (size_t)(KPG + 1) * 64;
  float* qp0  = ws + off; off += (size_t)QNB0 * 1024;
  float* qp1  = ws + off; off += (size_t)QNB1 * 256;
  float* qz0  = ws + off; off += (size_t)QNB0 * 4;
  float* qz1  = ws + off; off += (size_t)QNB1 * 4;
  float* mm   = ws + off; off += 8;
  float* qrep = ws + off; off += 64;
  int*   nbr  = (int*)(ws + off); off += (size_t)KPG * MAXD;
  int*   deg  = (int*)(ws + off); off += KPG;
  unsigned char* mask = (unsigned char*)(ws + off);     // 1 MiB

  k_prep<<<NBLK_NORM + 137, 256, 0, stream>>>(pv, rv, qv, Win, Wg0, Wg1, s0,
                                              nfH, WinH, Wg0H, Wg1H, mm);
  k_simhres<<<256 + 324, 256, 0, stream>>>(nfH, pn, WinH, bin, mask, hres, hresH);
  k_nbrwh0<<<1296 + 256, 256, 0, stream>>>(hresH, Wg0H, mask, wh0H, nbr, deg);
  k_sd0<<<NN, 256, 0, stream>>>(wh0H, as0, ad0, sd0);
  k_gat0all<<<QNB0 + 2 * KPG, 256, 0, stream>>>(wh0H, sd0, nbr, deg, h1H, qp0, qz0);
  k_qfin0<<<NHEAD, 256, 0, stream>>>(qp0, qz0, h1H);
  k_gemm3s<1024><<<dim3(4, 81), 512, 0, stream>>>(h1H, Wg1H, wh1H, DHID);
  k_sd1<<<NN, 256, 0, stream>>>(wh1H, as1, ad1, sd1);
  k_gat1all<<<QNB1 + KPG, 256, 0, stream>>>(wh1H, sd1, nbr, deg, h2, qp1, qz1);
  k_qfin1<<<1, 256, 0, stream>>>(qp1, qz1, hres, Wrs, brs, qrep);
  k_score4<<<KPG / 4, 256, 0, stream>>>(h2, hres, Wrs, brs, Ws1, bs1, Ws2, bs2,
                                        s0, lmx, mm, qrep, out);
}

// Round 15
// 100.384 us; speedup vs baseline: 1.0943x; 1.0943x over previous
//
#include <hip/hip_runtime.h>
#include <math.h>

#define KPG    1024
#define KRN    4096
#define NN     5121      // KPG + KRN + 1
#define MPAD   5184      // 81 * 64, padded row count for MFMA GEMMs
#define DIN    128
#define DHID   256
#define DOUT   64
#define NHEAD  4
#define LALPHA 0.2f
#define SEMTH  0.7f
#define QNB0   128
#define QCH0   ((NN + QNB0 - 1) / QNB0)  // 41
#define QNB1   128
#define QCH1   ((NN + QNB1 - 1) / QNB1)  // 41
#define MAXD   32
#define NBLK_NORM ((NN + 1) / 2)         // 2561 two-row normalize blocks

typedef __bf16 bf16x8 __attribute__((ext_vector_type(8)));
typedef float  f32x4  __attribute__((ext_vector_type(4)));

__device__ __forceinline__ float wave_sum(float v){
  #pragma unroll
  for (int o = 32; o > 0; o >>= 1) v += __shfl_down(v, o, 64);
  return v;
}

__device__ __forceinline__ float lrelu(float x){ return x >= 0.f ? x : LALPHA * x; }

__device__ __forceinline__ void tobf(float v, __bf16& h, __bf16& l){
  h = (__bf16)v;
  l = (__bf16)(v - (float)h);
}

// bijective XCD swizzle over a linear grid of nwg blocks (m204)
__device__ __forceinline__ int swz_lin(int orig, int nwg){
  int q = nwg >> 3, r = nwg & 7, xcd = orig & 7, idx = orig >> 3;
  return (xcd < r ? xcd * (q + 1) : r * (q + 1) + (xcd - r) * q) + idx;
}

// ---- K1: merged prep: normalize rows -> nf planes; weight transpose -> W*H bf16
__global__ __launch_bounds__(256) void k_prep(const float* __restrict__ pv,
                                              const float* __restrict__ rv,
                                              const float* __restrict__ qv,
                                              const float* __restrict__ Win,
                                              const float* __restrict__ Wg0,
                                              const float* __restrict__ Wg1,
                                              __bf16* __restrict__ nfH,
                                              __bf16* __restrict__ nfL,
                                              __bf16* __restrict__ WinH,
                                              __bf16* __restrict__ Wg0H,
                                              __bf16* __restrict__ Wg1H){
  __shared__ float tile[64][65];
  __shared__ float w4[4];
  int b = blockIdx.x, t = threadIdx.x;
  if (b < NBLK_NORM){
    int i = b * 2 + (t >> 7);
    int tt = t & 127;
    float x = 0.f;
    if (i < NN){
      const float* src = (i < KPG) ? pv + (size_t)i * DIN
                       : (i < KPG + KRN) ? rv + (size_t)(i - KPG) * DIN : qv;
      x = src[tt];
    }
    float ss = wave_sum(x * x);
    if ((t & 63) == 0) w4[t >> 6] = ss;
    __syncthreads();
    if (i < NN){
      int rh = t >> 7;
      float norm = sqrtf(w4[2 * rh] + w4[2 * rh + 1]);
      float y = x / fmaxf(norm, 1e-12f);
      __bf16 h, l; tobf(y, h, l);
      nfH[(size_t)i * DIN + tt] = h;
      nfL[(size_t)i * DIN + tt] = l;
    }
  } else {
    int bb = b - NBLK_NORM;
    const float* W; __bf16 *TH; int K, N, tb;
    if (bb < 8){ W = Win; TH = WinH; K = DIN;  N = DHID; tb = bb; }
    else if (bb < 72){ W = Wg0; TH = Wg0H; K = DHID; N = 1024; tb = bb - 8; }
    else { W = Wg1; TH = Wg1H; K = 1024; N = DHID; tb = bb - 72; }
    int ntx = N >> 6;
    int kb = (tb / ntx) * 64, nb = (tb % ntx) * 64;
    int rr = t >> 6, cc = t & 63;
    #pragma unroll
    for (int i = 0; i < 16; ++i){
      int k = i * 4 + rr;
      tile[k][cc] = W[(size_t)(kb + k) * N + nb + cc];
    }
    __syncthreads();
    #pragma unroll
    for (int i = 0; i < 16; ++i){
      int n = i * 4 + rr;
      TH[(size_t)(nb + n) * K + kb + cc] = (__bf16)tile[cc][n];
    }
  }
}

#define MFMA(a,b,c) __builtin_amdgcn_mfma_f32_16x16x32_bf16(a, b, c, 0, 0, 0)

struct Acc { f32x4 a00, a01, a10, a11; };

// ---- LDS-staged MFMA core (4 waves, 64x64 tile, BK=64); X3 = bf16x3 emulation
template<int K, bool X3>
__device__ __forceinline__ Acc gemm_core(const __bf16* __restrict__ AH,
                                         const __bf16* __restrict__ AL,
                                         const __bf16* __restrict__ BH,
                                         const __bf16* __restrict__ BL,
                                         int rblk, int cblk,
                                         __bf16* sm){
  int t = threadIdx.x, w = t >> 6, l = t & 63;
  int lr = l & 15, lk = l >> 4;
  __bf16* sAh = sm;
  __bf16* sBh = sm + 4096;
  __bf16* sAl = sm + 8192;
  __bf16* sBl = sm + 12288;

  int srow = t >> 3, scol = t & 7;
  int e0 = srow * 64 + ((scol ^ (srow & 7)) * 8);
  int e1 = e0 + 32 * 64;
  size_t gA0 = (size_t)(rblk + srow) * K + scol * 8;
  size_t gA1 = gA0 + (size_t)32 * K;
  size_t gB0 = (size_t)(cblk + srow) * K + scol * 8;
  size_t gB1 = gB0 + (size_t)32 * K;

  int ar0 = (w >> 1) * 32 + lr, ar1 = ar0 + 16;
  int bc0 = (w & 1) * 32 + lr,  bc1 = bc0 + 16;

  Acc acc;
  #pragma unroll
  for (int r = 0; r < 4; ++r){ acc.a00[r]=0.f; acc.a01[r]=0.f; acc.a10[r]=0.f; acc.a11[r]=0.f; }

  int4 st0, st1, st4, st5, st2, st3, st6, st7;
  st0 = *(const int4*)(AH + gA0);
  st1 = *(const int4*)(AH + gA1);
  st4 = *(const int4*)(BH + gB0);
  st5 = *(const int4*)(BH + gB1);
  if (X3){
    st2 = *(const int4*)(AL + gA0);
    st3 = *(const int4*)(AL + gA1);
    st6 = *(const int4*)(BL + gB0);
    st7 = *(const int4*)(BL + gB1);
  }

  const int NSTEP = K / 64;
  #pragma unroll 1
  for (int s = 0; s < NSTEP; ++s){
    __syncthreads();
    *(int4*)(sAh + e0) = st0;  *(int4*)(sAh + e1) = st1;
    *(int4*)(sBh + e0) = st4;  *(int4*)(sBh + e1) = st5;
    if (X3){
      *(int4*)(sAl + e0) = st2;  *(int4*)(sAl + e1) = st3;
      *(int4*)(sBl + e0) = st6;  *(int4*)(sBl + e1) = st7;
    }
    if (s + 1 < NSTEP){
      size_t ka = (size_t)(s + 1) * 64;
      st0 = *(const int4*)(AH + gA0 + ka);
      st1 = *(const int4*)(AH + gA1 + ka);
      st4 = *(const int4*)(BH + gB0 + ka);
      st5 = *(const int4*)(BH + gB1 + ka);
      if (X3){
        st2 = *(const int4*)(AL + gA0 + ka);
        st3 = *(const int4*)(AL + gA1 + ka);
        st6 = *(const int4*)(BL + gB0 + ka);
        st7 = *(const int4*)(BL + gB1 + ka);
      }
    }
    __syncthreads();
    #pragma unroll
    for (int kk = 0; kk < 2; ++kk){
      int pc = ((lk + kk * 4) ^ (lr & 7)) * 8;
      bf16x8 A0h = *(const bf16x8*)(sAh + ar0 * 64 + pc);
      bf16x8 A1h = *(const bf16x8*)(sAh + ar1 * 64 + pc);
      bf16x8 B0h = *(const bf16x8*)(sBh + bc0 * 64 + pc);
      bf16x8 B1h = *(const bf16x8*)(sBh + bc1 * 64 + pc);
      acc.a00 = MFMA(A0h, B0h, acc.a00);
      acc.a01 = MFMA(A0h, B1h, acc.a01);
      acc.a10 = MFMA(A1h, B0h, acc.a10);
      acc.a11 = MFMA(A1h, B1h, acc.a11);
      if (X3){
        bf16x8 A0l = *(const bf16x8*)(sAl + ar0 * 64 + pc);
        bf16x8 A1l = *(const bf16x8*)(sAl + ar1 * 64 + pc);
        bf16x8 B0l = *(const bf16x8*)(sBl + bc0 * 64 + pc);
        bf16x8 B1l = *(const bf16x8*)(sBl + bc1 * 64 + pc);
        acc.a00 = MFMA(A0h, B0l, acc.a00); acc.a00 = MFMA(A0l, B0h, acc.a00);
        acc.a01 = MFMA(A0h, B1l, acc.a01); acc.a01 = MFMA(A0l, B1h, acc.a01);
        acc.a10 = MFMA(A1h, B0l, acc.a10); acc.a10 = MFMA(A1l, B0h, acc.a10);
        acc.a11 = MFMA(A1h, B1l, acc.a11); acc.a11 = MFMA(A1l, B1h, acc.a11);
      }
    }
  }
  return acc;
}

// ---- K2: merged sim (bf16x3, 256 blocks) + hres GEMM (K=128, 324 blocks)
__global__ __launch_bounds__(256) void k_simhres(const __bf16* __restrict__ nfH,
                                                 const __bf16* __restrict__ nfL,
                                                 const int* __restrict__ pn,
                                                 const __bf16* __restrict__ WinH,
                                                 const float* __restrict__ bin,
                                                 unsigned char* __restrict__ mask,
                                                 float* __restrict__ hres,
                                                 __bf16* __restrict__ hresH){
  __shared__ __bf16 smem[16384];
  int b = blockIdx.x, t = threadIdx.x;
  int w = t >> 6, l = t & 63, lr = l & 15, lk = l >> 4;
  if (b < 256){
    int wg = swz_lin(b, 256);
    int rblk = (wg >> 4) * 64, cblk = (wg & 15) * 64;
    Acc acc = gemm_core<DIN, true>(nfH, nfL, nfH, nfL, rblk, cblk, smem);
    int rb = rblk + (w >> 1) * 32 + lk * 4;
    int cb = cblk + (w & 1) * 32 + lr;
    #pragma unroll
    for (int m = 0; m < 2; ++m){
      #pragma unroll
      for (int n = 0; n < 2; ++n){
        const f32x4& a = (m == 0) ? (n == 0 ? acc.a00 : acc.a01) : (n == 0 ? acc.a10 : acc.a11);
        int j = cb + n * 16;
        int pnj = pn[j];
        #pragma unroll
        for (int r = 0; r < 4; ++r){
          int i = rb + m * 16 + r;
          float s = a[r];
          int d = pn[i] - pnj;
          bool mb = ((s >= SEMTH) && (j != i)) || (d == 1) || (d == -1) || (j == i);
          mask[(size_t)i * KPG + j] = mb ? 1 : 0;
        }
      }
    }
  } else {
    int bb = swz_lin(b - 256, 324);
    int rblk = (bb >> 2) * 64, cblk = (bb & 3) * 64;
    Acc acc = gemm_core<DIN, false>(nfH, nullptr, WinH, nullptr, rblk, cblk, smem);
    int rb = rblk + (w >> 1) * 32 + lk * 4;
    int cb = cblk + (w & 1) * 32 + lr;
    #pragma unroll
    for (int m = 0; m < 2; ++m){
      #pragma unroll
      for (int n = 0; n < 2; ++n){
        const f32x4& a = (m == 0) ? (n == 0 ? acc.a00 : acc.a01) : (n == 0 ? acc.a10 : acc.a11);
        int col = cb + n * 16;
        float bv = bin[col];
        #pragma unroll
        for (int r = 0; r < 4; ++r){
          int row = rb + m * 16 + r;
          float v = a[r] + bv;
          size_t o = (size_t)row * DHID + col;
          hres[o] = v;
          hresH[o] = (__bf16)v;
        }
      }
    }
  }
}

// ---- K3: merged wh0 GEMM (1296 blocks) + neighbor-list compaction (256 blocks, 4 rows each)
__global__ __launch_bounds__(256) void k_nbrwh0(const __bf16* __restrict__ hresH,
                                                const __bf16* __restrict__ Wg0H,
                                                const unsigned char* __restrict__ mask,
                                                __bf16* __restrict__ wh0H,
                                                int* __restrict__ nbr,
                                                int* __restrict__ deg){
  __shared__ __bf16 smem[8192];
  int b = blockIdx.x, t = threadIdx.x;
  if (b < 1296){
    int wg = swz_lin(b, 1296);
    int rblk = (wg >> 4) * 64, cblk = (wg & 15) * 64;
    Acc acc = gemm_core<DHID, false>(hresH, nullptr, Wg0H, nullptr, rblk, cblk, smem);
    int w = t >> 6, l = t & 63, lr = l & 15, lk = l >> 4;
    int rb = rblk + (w >> 1) * 32 + lk * 4;
    int cb = cblk + (w & 1) * 32 + lr;
    #pragma unroll
    for (int m = 0; m < 2; ++m){
      #pragma unroll
      for (int n = 0; n < 2; ++n){
        const f32x4& a = (m == 0) ? (n == 0 ? acc.a00 : acc.a01) : (n == 0 ? acc.a10 : acc.a11);
        int col = cb + n * 16;
        #pragma unroll
        for (int r = 0; r < 4; ++r)
          wh0H[(size_t)(rb + m * 16 + r) * 1024 + col] = (__bf16)a[r];
      }
    }
  } else {
    int i = (b - 1296) * 4 + (t >> 6);
    int l = t & 63;
    const unsigned char* mrow = mask + (size_t)i * KPG;
    int off = 0;
    #pragma unroll
    for (int c = 0; c < 16; ++c){
      int j = c * 64 + l;
      bool bb = mrow[j] != 0;
      unsigned long long bal = __ballot(bb);
      int pos = off + __popcll(bal & ((1ull << l) - 1ull));
      if (bb && pos < MAXD) nbr[i * MAXD + pos] = j;
      off += __popcll(bal);
    }
    if (l == 0) deg[i] = (off > MAXD) ? MAXD : off;
  }
}

// ---- 8-wave in-block split-K(2) GEMM (wh1, K=1024)
template<int K>
__global__ __launch_bounds__(512) void k_gemm3s(const __bf16* __restrict__ AH,
                                                const __bf16* __restrict__ BH,
                                                __bf16* __restrict__ Cb,
                                                int N){
  __shared__ __bf16 smem[16384];
  int nwg = gridDim.x * gridDim.y;
  int orig = blockIdx.y * gridDim.x + blockIdx.x;
  int wg = swz_lin(orig, nwg);
  int bx = wg % gridDim.x, by = wg / gridDim.x;
  int rblk = by * 64, cblk = bx * 64;
  int t = threadIdx.x, kq = t >> 8, tl = t & 255;
  int w = t >> 6, quad = w & 3, l = t & 63;
  int lr = l & 15, lk = l >> 4;
  const int KH = K / 2;
  int kbase = kq * KH;

  __bf16* sAh = smem + kq * 8192;
  __bf16* sBh = sAh + 4096;

  int srow = tl >> 3, scol = tl & 7;
  int e0 = srow * 64 + ((scol ^ (srow & 7)) * 8);
  int e1 = e0 + 32 * 64;
  size_t gA0 = (size_t)(rblk + srow) * K + kbase + scol * 8;
  size_t gA1 = gA0 + (size_t)32 * K;
  size_t gB0 = (size_t)(cblk + srow) * K + kbase + scol * 8;
  size_t gB1 = gB0 + (size_t)32 * K;

  int ar0 = (quad >> 1) * 32 + lr, ar1 = ar0 + 16;
  int bc0 = (quad & 1) * 32 + lr,  bc1 = bc0 + 16;

  Acc acc;
  #pragma unroll
  for (int r = 0; r < 4; ++r){ acc.a00[r]=0.f; acc.a01[r]=0.f; acc.a10[r]=0.f; acc.a11[r]=0.f; }

  int4 st0 = *(const int4*)(AH + gA0);
  int4 st1 = *(const int4*)(AH + gA1);
  int4 st4 = *(const int4*)(BH + gB0);
  int4 st5 = *(const int4*)(BH + gB1);

  const int NSTEP = KH / 64;
  #pragma unroll 1
  for (int s = 0; s < NSTEP; ++s){
    __syncthreads();
    *(int4*)(sAh + e0) = st0;  *(int4*)(sAh + e1) = st1;
    *(int4*)(sBh + e0) = st4;  *(int4*)(sBh + e1) = st5;
    if (s + 1 < NSTEP){
      size_t ka = (size_t)(s + 1) * 64;
      st0 = *(const int4*)(AH + gA0 + ka);
      st1 = *(const int4*)(AH + gA1 + ka);
      st4 = *(const int4*)(BH + gB0 + ka);
      st5 = *(const int4*)(BH + gB1 + ka);
    }
    __syncthreads();
    #pragma unroll
    for (int kk = 0; kk < 2; ++kk){
      int pc = ((lk + kk * 4) ^ (lr & 7)) * 8;
      bf16x8 A0h = *(const bf16x8*)(sAh + ar0 * 64 + pc);
      bf16x8 A1h = *(const bf16x8*)(sAh + ar1 * 64 + pc);
      bf16x8 B0h = *(const bf16x8*)(sBh + bc0 * 64 + pc);
      bf16x8 B1h = *(const bf16x8*)(sBh + bc1 * 64 + pc);
      acc.a00 = MFMA(A0h, B0h, acc.a00);
      acc.a01 = MFMA(A0h, B1h, acc.a01);
      acc.a10 = MFMA(A1h, B0h, acc.a10);
      acc.a11 = MFMA(A1h, B1h, acc.a11);
    }
  }

  __syncthreads();
  float* part = (float*)smem;
  int rbase = (quad >> 1) * 32, cbase = (quad & 1) * 32;
  #pragma unroll
  for (int m = 0; m < 2; ++m){
    #pragma unroll
    for (int n = 0; n < 2; ++n){
      const f32x4& a = (m == 0) ? (n == 0 ? acc.a00 : acc.a01) : (n == 0 ? acc.a10 : acc.a11);
      #pragma unroll
      for (int r = 0; r < 4; ++r)
        part[kq * 4096 + (rbase + m * 16 + lk * 4 + r) * 64 + cbase + n * 16 + lr] = a[r];
    }
  }
  __syncthreads();
  #pragma unroll
  for (int e = 0; e < 8; ++e){
    int idx = e * 512 + t;
    int row = idx >> 6, col = idx & 63;
    float v = part[idx] + part[4096 + idx];
    Cb[(size_t)(rblk + row) * N + cblk + col] = (__bf16)v;
  }
}

// ---- K5: s/d projections for layer 0
__global__ __launch_bounds__(256) void k_sd0(const __bf16* __restrict__ wh,
                                             const float* __restrict__ asrc,
                                             const float* __restrict__ adst,
                                             float* __restrict__ sd){
  int n = blockIdx.x, t = threadIdx.x, hh = t >> 6, l = t & 63;
  float s = 0.f, d = 0.f;
  #pragma unroll
  for (int k = 0; k < 4; ++k){
    int idx = hh * 256 + k * 64 + l;
    float v = (float)wh[(size_t)n * 1024 + idx];
    s += v * asrc[idx];
    d += v * adst[idx];
  }
  s = wave_sum(s); d = wave_sum(d);
  if (l == 0){ sd[n * 8 + hh] = s; sd[n * 8 + 4 + hh] = d; }
}

// ---- K6: merged GAT layer-0: query partials | pages | region-groups
__global__ __launch_bounds__(256) void k_gat0all(const __bf16* __restrict__ wh,
                                                 const float* __restrict__ sd,
                                                 const int* __restrict__ nbr,
                                                 const int* __restrict__ deg,
                                                 __bf16* __restrict__ h1H,
                                                 float* __restrict__ qpart,
                                                 float* __restrict__ qz){
  int b = blockIdx.x, t = threadIdx.x;
  if (b < QNB0){
    int bq = b;
    float sq[NHEAD];
    #pragma unroll
    for (int h = 0; h < NHEAD; ++h) sq[h] = sd[(size_t)(NN - 1) * 8 + h];
    int j0 = bq * QCH0, j1 = (j0 + QCH0 < NN) ? j0 + QCH0 : NN;
    float acc[NHEAD] = {0.f, 0.f, 0.f, 0.f};
    float z[NHEAD] = {0.f, 0.f, 0.f, 0.f};
    #pragma unroll 4
    for (int j = j0; j < j1; ++j){
      float4 d4 = *(const float4*)&sd[j * 8 + 4];
      float e0 = __expf(lrelu(sq[0] + d4.x));
      float e1 = __expf(lrelu(sq[1] + d4.y));
      float e2 = __expf(lrelu(sq[2] + d4.z));
      float e3 = __expf(lrelu(sq[3] + d4.w));
      z[0] += e0; z[1] += e1; z[2] += e2; z[3] += e3;
      size_t base = (size_t)j * 1024 + t;
      acc[0] += e0 * (float)wh[base];
      acc[1] += e1 * (float)wh[base + 256];
      acc[2] += e2 * (float)wh[base + 512];
      acc[3] += e3 * (float)wh[base + 768];
    }
    #pragma unroll
    for (int h = 0; h < NHEAD; ++h) qpart[(size_t)bq * 1024 + h * 256 + t] = acc[h];
    if (t == 0){
      #pragma unroll
      for (int h = 0; h < NHEAD; ++h) qz[bq * 4 + h] = z[h];
    }
  } else if (b < QNB0 + KPG){
    int i = b - QNB0;
    __shared__ int jl[MAXD + 5];
    __shared__ float wgt[NHEAD][MAXD + 5];
    __shared__ float izs[NHEAD];
    int nd = deg[i], cnt = nd + 5;
    if (t < cnt)
      jl[t] = (t < nd) ? nbr[i * MAXD + t]
                       : ((t < nd + 4) ? (KPG + 4 * i + (t - nd)) : (NN - 1));
    __syncthreads();
    if (t < 4 * cnt){
      int x = t >> 2, h = t & 3;
      wgt[h][x] = __expf(lrelu(sd[i * 8 + h] + sd[jl[x] * 8 + 4 + h]));
    }
    __syncthreads();
    if (t < NHEAD){
      float Z = 0.f;
      for (int x = 0; x < cnt; ++x) Z += wgt[t][x];
      izs[t] = 1.f / Z;
    }
    __syncthreads();
    float acc[NHEAD] = {0.f, 0.f, 0.f, 0.f};
    #pragma unroll 4
    for (int x = 0; x < cnt; ++x){
      size_t base = (size_t)jl[x] * 1024 + t;
      #pragma unroll
      for (int h = 0; h < NHEAD; ++h) acc[h] += wgt[h][x] * (float)wh[base + h * 256];
    }
    size_t ob = (size_t)i * 1024;
    #pragma unroll
    for (int h = 0; h < NHEAD; ++h){
      float v = acc[h] * izs[h];
      v = (v > 0.f) ? v : expm1f(v);
      h1H[ob + h * 256 + t] = (__bf16)v;
    }
  } else {
    int g = b - QNB0 - KPG;
    __shared__ float wgt2[4][NHEAD][6];
    int rb = KPG + 4 * g;
    if (t < 16){
      int r = t >> 2, h = t & 3;
      int i = rb + r;
      float si = sd[i * 8 + h];
      int jx[6] = {g, rb, rb + 1, rb + 2, rb + 3, NN - 1};
      float Z = 0.f, e[6];
      #pragma unroll
      for (int x = 0; x < 6; ++x){
        e[x] = __expf(lrelu(si + sd[jx[x] * 8 + 4 + h]));
        Z += e[x];
      }
      float iz = 1.f / Z;
      #pragma unroll
      for (int x = 0; x < 6; ++x) wgt2[r][h][x] = e[x] * iz;
    }
    __syncthreads();
    float acc[4][NHEAD] = {};
    int jx[6] = {g, rb, rb + 1, rb + 2, rb + 3, NN - 1};
    #pragma unroll
    for (int x = 0; x < 6; ++x){
      size_t base = (size_t)jx[x] * 1024 + t;
      #pragma unroll
      for (int h = 0; h < NHEAD; ++h){
        float v = (float)wh[base + h * 256];
        #pragma unroll
        for (int r = 0; r < 4; ++r) acc[r][h] += wgt2[r][h][x] * v;
      }
    }
    #pragma unroll
    for (int r = 0; r < 4; ++r){
      size_t ob = (size_t)(rb + r) * 1024;
      #pragma unroll
      for (int h = 0; h < NHEAD; ++h){
        float v = acc[r][h];
        v = (v > 0.f) ? v : expm1f(v);
        h1H[ob + h * 256 + t] = (__bf16)v;
      }
    }
  }
}

// ---- finish query row of h1 (one block per head)
__global__ __launch_bounds__(256) void k_qfin0(const float* __restrict__ qpart,
                                               const float* __restrict__ qz,
                                               __bf16* __restrict__ h1H){
  int h = blockIdx.x, t = threadIdx.x;
  float s = 0.f, Z = 0.f;
  #pragma unroll 4
  for (int b = 0; b < QNB0; ++b){
    s += qpart[(size_t)b * 1024 + h * 256 + t];
    Z += qz[b * 4 + h];
  }
  float v = s / Z;
  v = (v > 0.f) ? v : expm1f(v);
  h1H[(size_t)(NN - 1) * 1024 + h * 256 + t] = (__bf16)v;
}

// ---- K8: s/d projections for layer 1
__global__ __launch_bounds__(256) void k_sd1(const __bf16* __restrict__ wh,
                                             const float* __restrict__ asrc,
                                             const float* __restrict__ adst,
                                             float* __restrict__ sd){
  int n = blockIdx.x, t = threadIdx.x, hh = t >> 6, l = t & 63;
  float v = (float)wh[(size_t)n * 256 + hh * 64 + l];
  float s = wave_sum(v * asrc[hh * 64 + l]);
  float d = wave_sum(v * adst[hh * 64 + l]);
  if (l == 0){ sd[n * 8 + hh] = s; sd[n * 8 + 4 + hh] = d; }
}

// ---- K9: merged GAT layer-1: query partials | pages
__global__ __launch_bounds__(256) void k_gat1all(const __bf16* __restrict__ wh,
                                                 const float* __restrict__ sd,
                                                 const int* __restrict__ nbr,
                                                 const int* __restrict__ deg,
                                                 float* __restrict__ h2,
                                                 float* __restrict__ qpart,
                                                 float* __restrict__ qz){
  int b = blockIdx.x, t = threadIdx.x, hh = t >> 6;
  if (b < QNB1){
    int bq = b;
    float sq = sd[(size_t)(NN - 1) * 8 + hh];
    int j0 = bq * QCH1, j1 = (j0 + QCH1 < NN) ? j0 + QCH1 : NN;
    float acc = 0.f, z = 0.f;
    #pragma unroll 4
    for (int j = j0; j < j1; ++j){
      float e = __expf(lrelu(sq + sd[j * 8 + 4 + hh]));
      z += e;
      acc += e * (float)wh[(size_t)j * 256 + t];
    }
    qpart[(size_t)bq * 256 + t] = acc;
    if ((t & 63) == 0) qz[bq * 4 + hh] = z;
  } else {
    int i = b - QNB1;
    __shared__ int jl[MAXD + 5];
    __shared__ float wgt[NHEAD][MAXD + 5];
    __shared__ float izs[NHEAD];
    int nd = deg[i], cnt = nd + 5;
    if (t < cnt)
      jl[t] = (t < nd) ? nbr[i * MAXD + t]
                       : ((t < nd + 4) ? (KPG + 4 * i + (t - nd)) : (NN - 1));
    __syncthreads();
    if (t < 4 * cnt){
      int x = t >> 2, h = t & 3;
      wgt[h][x] = __expf(lrelu(sd[i * 8 + h] + sd[jl[x] * 8 + 4 + h]));
    }
    __syncthreads();
    if (t < NHEAD){
      float Z = 0.f;
      for (int x = 0; x < cnt; ++x) Z += wgt[t][x];
      izs[t] = 1.f / Z;
    }
    __syncthreads();
    float acc = 0.f;
    #pragma unroll 4
    for (int x = 0; x < cnt; ++x)
      acc += wgt[hh][x] * (float)wh[(size_t)jl[x] * 256 + t];
    acc *= izs[hh];
    __shared__ float col[256];
    col[t] = acc;
    __syncthreads();
    if (t < 64)
      h2[(size_t)i * 64 + t] = 0.25f * (col[t] + col[64 + t] + col[128 + t] + col[192 + t]);
  }
}

// ---- finish query row of h2 (normalize partials) + stage1 min/max
__global__ __launch_bounds__(256) void k_qfin1mm(const float* __restrict__ qpart,
                                                 const float* __restrict__ qz,
                                                 const float* __restrict__ s0,
                                                 float* __restrict__ h2,
                                                 float* __restrict__ mm){
  int t = threadIdx.x, hh = t >> 6;
  float mn = 1e30f, mx = -1e30f;
  for (int j = t; j < KPG; j += 256){
    float v = s0[j];
    mn = fminf(mn, v); mx = fmaxf(mx, v);
  }
  __shared__ float smn[256], smx[256];
  smn[t] = mn; smx[t] = mx;
  __syncthreads();
  for (int s = 128; s > 0; s >>= 1){
    if (t < s){ smn[t] = fminf(smn[t], smn[t + s]); smx[t] = fmaxf(smx[t], smx[t + s]); }
    __syncthreads();
  }
  if (t == 0){ mm[0] = smn[0]; mm[1] = smx[0]; }
  float s = 0.f, Z = 0.f;
  #pragma unroll 4
  for (int b = 0; b < QNB1; ++b){
    s += qpart[(size_t)b * 256 + t];
    Z += qz[b * 4 + hh];
  }
  __shared__ float col[256];
  col[t] = s / Z;
  __syncthreads();
  if (t < 64)
    h2[(size_t)KPG * 64 + t] = 0.25f * (col[t] + col[64 + t] + col[128 + t] + col[192 + t]);
}

// ---- K12: scoring MLP + residual (recomputed in-block) + mix
__global__ __launch_bounds__(64) void k_score2(const float* __restrict__ h2,
                                               const float* __restrict__ hres,
                                               const float* __restrict__ Wres,
                                               const float* __restrict__ bres,
                                               const float* __restrict__ Ws1,
                                               const float* __restrict__ bs1,
                                               const float* __restrict__ Ws2,
                                               const float* __restrict__ bs2,
                                               const float* __restrict__ s0,
                                               const float* __restrict__ lmix,
                                               const float* __restrict__ mm,
                                               float* __restrict__ out){
  int i = blockIdx.x, t = threadIdx.x;
  __shared__ float hrow[DHID], hq[DHID], pg[64], qr[64];
  #pragma unroll
  for (int k = 0; k < 4; ++k){
    hrow[k * 64 + t] = hres[(size_t)i * DHID + k * 64 + t];
    hq[k * 64 + t]   = hres[(size_t)(NN - 1) * DHID + k * 64 + t];
  }
  __syncthreads();
  float ri = bres[t], rq = bres[t];
  #pragma unroll 8
  for (int d = 0; d < DHID; ++d){
    float w = Wres[d * 64 + t];
    ri += hrow[d] * w;
    rq += hq[d] * w;
  }
  pg[t] = h2[(size_t)i * 64 + t] + ri;
  qr[t] = h2[(size_t)KPG * 64 + t] + rq;
  __syncthreads();
  float z = bs1[t];
  #pragma unroll 8
  for (int d = 0; d < 64; ++d){
    z += pg[d] * Ws1[d * 64 + t];
    z += qr[d] * Ws1[(64 + d) * 64 + t];
  }
  z = fmaxf(z, 0.f);
  float v = wave_sum(z * Ws2[t]);
  if (t == 0){
    float delta = v + bs2[0];
    float mn = mm[0], mx = mm[1];
    float s0n = (s0[i] - mn) / (mx - mn + 1e-8f);
    float lam = 1.f / (1.f + __expf(-lmix[0]));
    out[i] = (1.f - lam) * s0n + lam * delta;
  }
}

extern "C" void kernel_launch(void* const* d_in, const int* in_sizes, int n_in,
                              void* d_out, int out_size, void* d_ws, size_t ws_size,
                              hipStream_t stream){
  const float* pv  = (const float*)d_in[0];
  const float* rv  = (const float*)d_in[1];
  const float* qv  = (const float*)d_in[2];
  const int*   pn  = (const int*)d_in[3];
  const float* s0  = (const float*)d_in[4];
  const float* Win = (const float*)d_in[5];
  const float* bin = (const float*)d_in[6];
  const float* Wg0 = (const float*)d_in[7];
  const float* as0 = (const float*)d_in[8];
  const float* ad0 = (const float*)d_in[9];
  const float* Wg1 = (const float*)d_in[10];
  const float* as1 = (const float*)d_in[11];
  const float* ad1 = (const float*)d_in[12];
  const float* Wrs = (const float*)d_in[13];
  const float* brs = (const float*)d_in[14];
  const float* Ws1 = (const float*)d_in[15];
  const float* bs1 = (const float*)d_in[16];
  const float* Ws2 = (const float*)d_in[17];
  const float* bs2 = (const float*)d_in[18];
  const float* lmx = (const float*)d_in[19];
  float* out = (float*)d_out;

  float* ws = (float*)d_ws;
  size_t off = 0;
  __bf16* nfH = (__bf16*)(ws + off); off += (size_t)MPAD * DIN / 2;
  __bf16* nfL = (__bf16*)(ws + off); off += (size_t)MPAD * DIN / 2;
  __bf16* WinH = (__bf16*)(ws + off); off += (size_t)DHID * DIN / 2;
  __bf16* Wg0H = (__bf16*)(ws + off); off += (size_t)1024 * DHID / 2;
  __bf16* Wg1H = (__bf16*)(ws + off); off += (size_t)DHID * 1024 / 2;
  float* hres = ws + off; off += (size_t)MPAD * DHID;
  __bf16* hresH = (__bf16*)(ws + off); off += (size_t)MPAD * DHID / 2;
  __bf16* wh0H = (__bf16*)(ws + off); off += (size_t)MPAD * 1024 / 2;
  __bf16* h1H  = (__bf16*)(ws + off); off += (size_t)MPAD * 1024 / 2;
  __bf16* wh1H = (__bf16*)(ws + off); off += (size_t)MPAD * 256 / 2;
  float* sd0  = ws + off; off += (size_t)NN * 8;
  float* sd1  = ws + off; off += (size_t)NN * 8;
  float* h2   = ws + off; off += (size_t)(KPG + 1) * 64;
  float* qp0  = ws + off; off += (size_t)QNB0 * 1024;
  float* qp1  = ws + off; off += (size_t)QNB1 * 256;
  float* qz0  = ws + off; off += (size_t)QNB0 * 4;
  float* qz1  = ws + off; off += (size_t)QNB1 * 4;
  float* mm   = ws + off; off += 8;
  int*   nbr  = (int*)(ws + off); off += (size_t)KPG * MAXD;
  int*   deg  = (int*)(ws + off); off += KPG;
  unsigned char* mask = (unsigned char*)(ws + off);     // 1 MiB

  k_prep<<<NBLK_NORM + 136, 256, 0, stream>>>(pv, rv, qv, Win, Wg0, Wg1,
                                              nfH, nfL, WinH, Wg0H, Wg1H);
  k_simhres<<<256 + 324, 256, 0, stream>>>(nfH, nfL, pn, WinH, bin, mask, hres, hresH);
  k_nbrwh0<<<1296 + 256, 256, 0, stream>>>(hresH, Wg0H, mask, wh0H, nbr, deg);
  k_sd0<<<NN, 256, 0, stream>>>(wh0H, as0, ad0, sd0);
  k_gat0all<<<QNB0 + 2 * KPG, 256, 0, stream>>>(wh0H, sd0, nbr, deg, h1H, qp0, qz0);
  k_qfin0<<<NHEAD, 256, 0, stream>>>(qp0, qz0, h1H);
  k_gemm3s<1024><<<dim3(4, 81), 512, 0, stream>>>(h1H, Wg1H, wh1H, DHID);
  k_sd1<<<NN, 256, 0, stream>>>(wh1H, as1, ad1, sd1);
  k_gat1all<<<QNB1 + KPG, 256, 0, stream>>>(wh1H, sd1, nbr, deg, h2, qp1, qz1);
  k_qfin1mm<<<1, 256, 0, stream>>>(qp1, qz1, s0, h2, mm);
  k_score2<<<KPG, 64, 0, stream>>>(h2, hres, Wrs, brs, Ws1, bs1, Ws2, bs2, s0, lmx, mm, out);
}